// Round 11
// baseline (392.816 us; speedup 1.0000x reference)
//
#include <hip/hip_runtime.h>
#include <hip/hip_bf16.h>
#include <type_traits>

// Problem dims (fixed by setup_inputs)
#define B_   4
#define T_   4096
#define D_   512
#define E_   2048          // D_inner
#define M_   (B_*T_)       // 16384 rows
#define N1_  (2*E_)        // 4096 (reordered hidden/gate cols)
#define K1_  D_            // 512
#define N2_  D_            // 512
#define K2_  E_            // 2048
#define CT_  128           // scan chunk length
#define NC_  (T_/CT_)      // 32 chunks

typedef __attribute__((ext_vector_type(8))) short short8_t;
typedef __attribute__((ext_vector_type(4))) float f32x4;

__device__ inline unsigned short f2bf(float f){
  unsigned u = __float_as_uint(f);
  u += 0x7fffu + ((u >> 16) & 1u);      // RNE
  return (unsigned short)(u >> 16);
}
__device__ inline float bf2f(unsigned h){ return __uint_as_float(h << 16); }
__device__ inline float fast_rcp(float x){
  float r; asm("v_rcp_f32 %0, %1" : "=v"(r) : "v"(x)); return r;
}
__device__ inline unsigned pk_bf16(float lo, float hi){
  unsigned r; asm("v_cvt_pk_bf16_f32 %0, %1, %2" : "=v"(r) : "v"(lo), "v"(hi)); return r;
}

template<int I, int N, typename F>
__device__ __forceinline__ void sfor(F&& f){
  if constexpr (I < N) { f(std::integral_constant<int, I>{}); sfor<I + 1, N>(f); }
}

// ---------------------------------------------------------------- converts
__global__ __launch_bounds__(256) void conv_f32_bf16_x4(const float* __restrict__ in,
                                                        short* __restrict__ out, int n4){
  int i = blockIdx.x * 256 + threadIdx.x;
  if (i >= n4) return;
  float4 v = ((const float4*)in)[i];
  short4 o;
  o.x = (short)f2bf(v.x); o.y = (short)f2bf(v.y);
  o.z = (short)f2bf(v.z); o.w = (short)f2bf(v.w);
  ((short4*)out)[i] = o;
}

// W_hg [4096,512] -> Wp reordered: within each 64-col wave tile,
// cols 0..31 = hidden rows e_base..e_base+31, cols 32..63 = matching gate rows.
__global__ __launch_bounds__(128) void conv_whg(const float* __restrict__ W,
                                                short* __restrict__ Wp){
  int r = blockIdx.x;                                  // 0..4095
  int e = ((r >> 6) << 5) + (r & 31);
  int orig = e + ((r >> 5) & 1) * E_;
  float4 v = ((const float4*)(W + (size_t)orig * K1_))[threadIdx.x];
  short4 o;
  o.x = (short)f2bf(v.x); o.y = (short)f2bf(v.y);
  o.z = (short)f2bf(v.z); o.w = (short)f2bf(v.w);
  ((short4*)(Wp + (size_t)r * K1_))[threadIdx.x] = o;
}

// ---------------------------------------------------------------- GEMM (B^T layout)
// 128x128 tile, BK=64, 4 waves. R10 PMC showed the old both-operands-in-LDS
// version is LDS-pipe-bound (98k cyc ds_read vs 79.5k MFMA per CU). Changes:
//  * A operand read DIRECTLY from global (L2-resident via the 2D XCD swizzle;
//    swizzle algebra cancels: af[m] = A[brow+wr+m*16+l15][kt+kk+kh], 16B/lane,
//    constexpr offsets). Halves LDS reads + staging writes.
//  * Only B is LDS-staged (dbuf 32KB/block -> 3 blocks/CU, launch_bounds(256,3)).
//  * A-loads issued BEFORE the B-stage each iter so MFMA's counted vmcnt waits
//    never drain the in-flight B stages; __syncthreads drains them after MFMA.
//  * Normal stores (R10: NT stores amplified writes 131->171MB and regressed).
template<int EPI, int KK>
__global__ __launch_bounds__(256, 3)
void gemm_db(const short* __restrict__ A, const short* __restrict__ Bmat,
             const float* __restrict__ bias,
             unsigned* __restrict__ ab_out,
             float* __restrict__ c_out, int ldc)
{
  __shared__ short Bs[2][128 * 64];
  constexpr int NT = KK / 64;

  const int tid  = threadIdx.x;
  const int lane = tid & 63;
  const int w    = tid >> 6;
  const int wr   = (w >> 1) * 64;
  const int wc   = (w & 1) * 64;

  // --- 2D-chunked XCD swizzle (nwg%8==0, per-XCD chunk covers 16 brows) ---
  const int gx  = gridDim.x;
  const int nwg = gx * gridDim.y;
  const int lin = blockIdx.y * gx + blockIdx.x;
  const int cp  = nwg >> 3;                 // blocks per XCD chunk
  const int xcd = lin & 7;
  const int q   = lin >> 3;                 // position within chunk
  const int TW  = (gx < 8) ? gx : 8;        // tile width (bcol dir)
  const int TH  = 64 / TW;                  // tile height (brow dir)
  const int tile = q >> 6, s = q & 63;      // 64-block tiles
  const int tpb  = gx / TW;                 // tiles per brow-band
  const int band = tile / tpb, tb = tile - band * tpb;
  const int browL = band * TH + s / TW;
  const int bcol  = (tb * TW + (s % TW)) * 128;
  const int brow  = (xcd * (cp / gx) + browL) * 128;

  f32x4 acc[4][4];
  #pragma unroll
  for (int m = 0; m < 4; ++m)
    #pragma unroll
    for (int n = 0; n < 4; ++n) acc[m][n] = (f32x4){0.f, 0.f, 0.f, 0.f};

  const int srow = lane >> 3;
  const int scol = ((lane & 7) ^ srow) * 8;   // pre-swizzled global col (B staging)
  const int l15  = lane & 15;
  const int kh   = (lane >> 4) * 8;
  const int sw   = (l15 & 7) << 3;            // ds_read XOR (shorts)

  // A row pointers: direct global->reg fragments (swizzle-free addressing)
  const short* gA[4];
  #pragma unroll
  for (int m = 0; m < 4; ++m)
    gA[m] = A + (size_t)(brow + wr + m * 16 + l15) * KK + kh;

  // B staging base addresses (4 rows-of-8 per wave)
  const short* gb[4];
  #pragma unroll
  for (int i = 0; i < 4; ++i)
    gb[i] = Bmat + (size_t)(bcol + (w * 4 + i) * 8 + srow) * KK + scol;

  short8_t af[4][2];
  auto loadA = [&](auto TT) {
    constexpr int kt = decltype(TT)::value * 64;     // shorts
    #pragma unroll
    for (int m = 0; m < 4; ++m) {
      af[m][0] = *(const short8_t*)(gA[m] + kt);
      af[m][1] = *(const short8_t*)(gA[m] + kt + 32);
    }
  };
  auto stageB = [&](auto CUR, auto TT) {
    constexpr int cb = decltype(CUR)::value;
    constexpr int kt = decltype(TT)::value * 64;     // shorts
    #pragma unroll
    for (int i = 0; i < 4; ++i)
      __builtin_amdgcn_global_load_lds(
          (const __attribute__((address_space(1))) void*)(gb[i] + kt),
          (__attribute__((address_space(3))) void*)&Bs[cb][(w * 4 + i) * 512], 16, 0, 0);
  };
  auto comp = [&](auto CUR) {
    constexpr int cb = decltype(CUR)::value;
    #pragma unroll
    for (int kx = 0; kx < 2; ++kx) {
      const int kk = kx * 32;
      short8_t bfr[4];
      #pragma unroll
      for (int n = 0; n < 4; ++n)
        bfr[n] = *(const short8_t*)&Bs[cb][(wc + n * 16 + l15) * 64 + ((kk + kh) ^ sw)];
      #pragma unroll
      for (int m = 0; m < 4; ++m)
        #pragma unroll
        for (int n = 0; n < 4; ++n)
          acc[m][n] = __builtin_amdgcn_mfma_f32_16x16x32_bf16(af[m][kx], bfr[n], acc[m][n], 0, 0, 0);
    }
  };

  stageB(std::integral_constant<int, 0>{}, std::integral_constant<int, 0>{});
  __syncthreads();

  sfor<0, NT>([&](auto TT) {
    constexpr int t   = decltype(TT)::value;
    constexpr int cur = t & 1;
    loadA(TT);                                      // A loads FIRST (issue order)
    if constexpr (t + 1 < NT)
      stageB(std::integral_constant<int, cur ^ 1>{}, std::integral_constant<int, t + 1>{});
    comp(std::integral_constant<int, cur>{});
    if constexpr (t + 1 < NT) __syncthreads();
  });

  const int r4 = (lane >> 4) * 4;
  if constexpr (EPI == 0) {
    // cols [wc..wc+31] = hidden(e), [wc+32..wc+63] = gate(e): same lane holds both
    const int ebase = (bcol + wc) >> 1;
    #pragma unroll
    for (int m = 0; m < 4; ++m) {
      const int row = brow + wr + m * 16 + r4;
      #pragma unroll
      for (int n = 0; n < 2; ++n) {
        const int e = ebase + n * 16 + l15;
        const float bh = bias[e];
        const float bg = bias[E_ + e];
        #pragma unroll
        for (int j = 0; j < 4; ++j) {
          float hh = acc[m][n][j]     + bh;   // hidden pre-activation
          float gg = acc[m][n + 2][j] + bg;   // gate pre-activation
          float r  = fast_rcp(1.f + __expf(-fabsf(gg)));
          float z  = (gg >= 0.f) ? r : 1.f - r;   // sigmoid(gg)
          float a  = 1.f - z;                     // sigmoid(-gg)
          float gf = (hh >= 0.f) ? (hh + 0.5f) : fast_rcp(1.f + __expf(-hh));
          float bb = z * gf;
          ab_out[(size_t)(row + j) * E_ + e] = pk_bf16(a, bb);
        }
      }
    }
  } else {
    #pragma unroll
    for (int m = 0; m < 4; ++m) {
      #pragma unroll
      for (int n = 0; n < 4; ++n) {
        const int row = brow + wr + m * 16 + r4;
        const int col = bcol + wc + n * 16 + l15;
        #pragma unroll
        for (int j = 0; j < 4; ++j)
          c_out[(size_t)(row + j) * ldc + col] = acc[m][n][j] + bias[col];
      }
    }
  }
}

// ---------------------------------------------------------------- scan (3-pass)
__global__ __launch_bounds__(256) void scan_chunk(const unsigned* __restrict__ ab,
                                                  float* __restrict__ Ac,
                                                  float* __restrict__ Bc){
  const int c = blockIdx.x;
  const int e = (blockIdx.y * 256 + threadIdx.x) * 4;
  const int b = blockIdx.z;
  size_t base = (((size_t)b * T_ + (size_t)c * CT_) * E_ + e) >> 2;  // uint4 index
  const uint4* abv = (const uint4*)ab;
  float A0=1.f,A1=1.f,A2=1.f,A3=1.f, H0=0.f,H1=0.f,H2=0.f,H3=0.f;
  #pragma unroll 4
  for (int t = 0; t < CT_; ++t) {
    uint4 wv = abv[base + (size_t)t * (E_ / 4)];
    float a0=bf2f(wv.x&0xffffu), b0=bf2f(wv.x>>16);
    float a1=bf2f(wv.y&0xffffu), b1=bf2f(wv.y>>16);
    float a2=bf2f(wv.z&0xffffu), b2=bf2f(wv.z>>16);
    float a3=bf2f(wv.w&0xffffu), b3=bf2f(wv.w>>16);
    H0=fmaf(a0,H0,b0); H1=fmaf(a1,H1,b1); H2=fmaf(a2,H2,b2); H3=fmaf(a3,H3,b3);
    A0*=a0; A1*=a1; A2*=a2; A3*=a3;
  }
  size_t ci = (((size_t)b * NC_ + c) * E_ + e) >> 2;
  ((float4*)Ac)[ci] = (float4){A0,A1,A2,A3};
  ((float4*)Bc)[ci] = (float4){H0,H1,H2,H3};
}

// Initial hidden state is 1.0 (reference pads log_values with 0 -> exp(0)=1).
__global__ __launch_bounds__(256) void scan_carry(const float* __restrict__ Ac,
                                                  const float* __restrict__ Bc,
                                                  float* __restrict__ Hc){
  int idx = blockIdx.x * 256 + threadIdx.x;   // 0..B_*E_-1
  int b = idx >> 11;                          // /E_
  int e = idx & (E_ - 1);
  float H = 1.f;                              // h_0 = 1 !
  for (int c = 0; c < NC_; ++c) {
    size_t ci = ((size_t)b * NC_ + c) * E_ + e;
    float A = Ac[ci], Bv = Bc[ci];
    Hc[ci] = H;                               // carry-in for chunk c
    H = fmaf(A, H, Bv);
  }
}

__global__ __launch_bounds__(256) void scan_final(const unsigned* __restrict__ ab,
                                                  const float* __restrict__ Hc,
                                                  short* __restrict__ h){
  const int c = blockIdx.x;
  const int e = (blockIdx.y * 256 + threadIdx.x) * 4;
  const int b = blockIdx.z;
  size_t base = (((size_t)b * T_ + (size_t)c * CT_) * E_ + e) >> 2;
  const uint4* abv = (const uint4*)ab;
  float4 Hv = ((const float4*)Hc)[(((size_t)b * NC_ + c) * E_ + e) >> 2];
  float H0=Hv.x, H1=Hv.y, H2=Hv.z, H3=Hv.w;
  short4* hv = (short4*)h;
  #pragma unroll 4
  for (int t = 0; t < CT_; ++t) {
    uint4 wv = abv[base + (size_t)t * (E_ / 4)];
    H0 = fmaf(bf2f(wv.x&0xffffu), H0, bf2f(wv.x>>16));
    H1 = fmaf(bf2f(wv.y&0xffffu), H1, bf2f(wv.y>>16));
    H2 = fmaf(bf2f(wv.z&0xffffu), H2, bf2f(wv.z>>16));
    H3 = fmaf(bf2f(wv.w&0xffffu), H3, bf2f(wv.w>>16));
    short4 o;
    o.x=(short)f2bf(H0); o.y=(short)f2bf(H1); o.z=(short)f2bf(H2); o.w=(short)f2bf(H3);
    hv[base + (size_t)t * (E_ / 4)] = o;
  }
}

// ---------------------------------------------------------------- launch
extern "C" void kernel_launch(void* const* d_in, const int* in_sizes, int n_in,
                              void* d_out, int out_size, void* d_ws, size_t ws_size,
                              hipStream_t stream)
{
  const float* x     = (const float*)d_in[0];
  const float* W_hg  = (const float*)d_in[1];
  const float* b_hg  = (const float*)d_in[2];
  const float* W_out = (const float*)d_in[3];
  const float* b_out = (const float*)d_in[4];
  float* out = (float*)d_out;

  char* p = (char*)d_ws;
  auto carve = [&](size_t bytes) -> char* {
    char* q = p; p += (bytes + 255) & ~(size_t)255; return q;
  };
  short*    xb   = (short*)   carve((size_t)M_ * K1_ * 2);   // 16.8 MB
  short*    Wp   = (short*)   carve((size_t)N1_ * K1_ * 2);  //  4.2 MB
  short*    Wo   = (short*)   carve((size_t)N2_ * K2_ * 2);  //  2.1 MB
  unsigned* ab   = (unsigned*)carve((size_t)M_ * E_ * 4);    // 134.2 MB
  short*    hbuf = (short*)   carve((size_t)M_ * E_ * 2);    // 67.1 MB
  float*    Ac   = (float*)   carve((size_t)B_ * NC_ * E_ * 4);
  float*    Bc   = (float*)   carve((size_t)B_ * NC_ * E_ * 4);
  float*    Hc   = (float*)   carve((size_t)B_ * NC_ * E_ * 4);

  conv_f32_bf16_x4<<<(M_ * K1_ / 4 + 255) / 256, 256, 0, stream>>>(x, xb, M_ * K1_ / 4);
  conv_whg<<<N1_, 128, 0, stream>>>(W_hg, Wp);
  conv_f32_bf16_x4<<<(N2_ * K2_ / 4 + 255) / 256, 256, 0, stream>>>(W_out, Wo, N2_ * K2_ / 4);

  gemm_db<0, K1_><<<dim3(N1_ / 128, M_ / 128), 256, 0, stream>>>(xb, Wp, b_hg, ab, nullptr, 0);

  scan_chunk<<<dim3(NC_, E_ / 1024, B_), 256, 0, stream>>>(ab, Ac, Bc);
  scan_carry<<<(B_ * E_) / 256, 256, 0, stream>>>(Ac, Bc, Hc);
  scan_final<<<dim3(NC_, E_ / 1024, B_), 256, 0, stream>>>(ab, Hc, hbuf);

  gemm_db<1, K2_><<<dim3(N2_ / 128, M_ / 128), 256, 0, stream>>>(hbuf, Wo, b_out, nullptr, out, N2_);
}

// Round 12
// 296.390 us; speedup vs baseline: 1.3253x; 1.3253x over previous
//
#include <hip/hip_runtime.h>
#include <hip/hip_bf16.h>
#include <type_traits>

// Problem dims (fixed by setup_inputs)
#define B_   4
#define T_   4096
#define D_   512
#define E_   2048          // D_inner
#define M_   (B_*T_)       // 16384 rows
#define N1_  (2*E_)        // 4096 (reordered hidden/gate cols)
#define K1_  D_            // 512
#define N2_  D_            // 512
#define K2_  E_            // 2048
#define CT_  128           // scan chunk length
#define NC_  (T_/CT_)      // 32 chunks

typedef __attribute__((ext_vector_type(8))) short short8_t;
typedef __attribute__((ext_vector_type(4))) float f32x4;

__device__ inline unsigned short f2bf(float f){
  unsigned u = __float_as_uint(f);
  u += 0x7fffu + ((u >> 16) & 1u);      // RNE
  return (unsigned short)(u >> 16);
}
__device__ inline float bf2f(unsigned h){ return __uint_as_float(h << 16); }
__device__ inline float fast_rcp(float x){
  float r; asm("v_rcp_f32 %0, %1" : "=v"(r) : "v"(x)); return r;
}
__device__ inline unsigned pk_bf16(float lo, float hi){
  unsigned r; asm("v_cvt_pk_bf16_f32 %0, %1, %2" : "=v"(r) : "v"(lo), "v"(hi)); return r;
}

template<int I, int N, typename F>
__device__ __forceinline__ void sfor(F&& f){
  if constexpr (I < N) { f(std::integral_constant<int, I>{}); sfor<I + 1, N>(f); }
}

// ---------------------------------------------------------------- converts
__global__ __launch_bounds__(256) void conv_f32_bf16_x4(const float* __restrict__ in,
                                                        short* __restrict__ out, int n4){
  int i = blockIdx.x * 256 + threadIdx.x;
  if (i >= n4) return;
  float4 v = ((const float4*)in)[i];
  short4 o;
  o.x = (short)f2bf(v.x); o.y = (short)f2bf(v.y);
  o.z = (short)f2bf(v.z); o.w = (short)f2bf(v.w);
  ((short4*)out)[i] = o;
}

// W_hg [4096,512] -> Wp reordered: within each 64-col wave tile,
// cols 0..31 = hidden rows e_base..e_base+31, cols 32..63 = matching gate rows.
__global__ __launch_bounds__(128) void conv_whg(const float* __restrict__ W,
                                                short* __restrict__ Wp){
  int r = blockIdx.x;                                  // 0..4095
  int e = ((r >> 6) << 5) + (r & 31);
  int orig = e + ((r >> 5) & 1) * E_;
  float4 v = ((const float4*)(W + (size_t)orig * K1_))[threadIdx.x];
  short4 o;
  o.x = (short)f2bf(v.x); o.y = (short)f2bf(v.y);
  o.z = (short)f2bf(v.z); o.w = (short)f2bf(v.w);
  ((short4*)(Wp + (size_t)r * K1_))[threadIdx.x] = o;
}

// ---------------------------------------------------------------- GEMM (B^T layout)
// R8 structure (proven 116.8us): 128x128 tile, BK=64, 4 waves, BOTH operands
// LDS-staged via global_load_lds (R11 showed A-direct-from-global regresses:
// 16-segment scattered loads + raw L2 latency in the inner loop). Double-
// buffered (64KiB -> 2 blocks/CU), ONE barrier per K-step, stage(t+1) issued
// before compute(t). XOR-swizzled LDS via pre-swizzled global src + swizzled
// ds_read. K fully unrolled, kt folded into pointer (builtin offset MUST be 0).
// + 2D-chunked XCD swizzle (R10-proven: FETCH 140->41MB = compulsory).
// + NORMAL stores (R10-proven: NT stores amplify writes 131->171MB, regress).
template<int EPI, int KK>
__global__ __launch_bounds__(256, 2)
void gemm_db(const short* __restrict__ A, const short* __restrict__ Bmat,
             const float* __restrict__ bias,
             unsigned* __restrict__ ab_out,
             float* __restrict__ c_out, int ldc)
{
  __shared__ short As[2][128 * 64];
  __shared__ short Bs[2][128 * 64];
  constexpr int NT = KK / 64;

  const int tid  = threadIdx.x;
  const int lane = tid & 63;
  const int w    = tid >> 6;
  const int wr   = (w >> 1) * 64;
  const int wc   = (w & 1) * 64;

  // --- 2D-chunked XCD swizzle (nwg%8==0, (nwg/8)%64==0, gx%TW==0) ---
  const int gx  = gridDim.x;
  const int nwg = gx * gridDim.y;
  const int lin = blockIdx.y * gx + blockIdx.x;
  const int cp  = nwg >> 3;                 // blocks per XCD chunk
  const int xcd = lin & 7;
  const int q   = lin >> 3;                 // position within chunk
  const int TW  = (gx < 8) ? gx : 8;        // tile width (bcol dir)
  const int TH  = 64 / TW;                  // tile height (brow dir)
  const int tile = q >> 6, s = q & 63;      // 64-block tiles
  const int tpb  = gx / TW;                 // tiles per brow-band
  const int band = tile / tpb, tb = tile - band * tpb;
  const int browL = band * TH + s / TW;
  const int bcol  = (tb * TW + (s % TW)) * 128;
  const int brow  = (xcd * (cp / gx) + browL) * 128;

  f32x4 acc[4][4];
  #pragma unroll
  for (int m = 0; m < 4; ++m)
    #pragma unroll
    for (int n = 0; n < 4; ++n) acc[m][n] = (f32x4){0.f, 0.f, 0.f, 0.f};

  const int srow = lane >> 3;
  const int scol = ((lane & 7) ^ srow) * 8;   // pre-swizzled global col (shorts)
  const int l15  = lane & 15;
  const int kh   = (lane >> 4) * 8;
  const int sw   = (l15 & 7) << 3;            // ds_read XOR (shorts)

  // 8 base addresses (4 per matrix); kt folded in as constexpr displacement
  const short* ga[4]; const short* gb[4];
  #pragma unroll
  for (int i = 0; i < 4; ++i) {
    const int rr = (w * 4 + i) * 8 + srow;
    ga[i] = A    + (size_t)(brow + rr) * KK + scol;
    gb[i] = Bmat + (size_t)(bcol + rr) * KK + scol;
  }

  auto stage = [&](auto CUR, auto TT) {
    constexpr int cb = decltype(CUR)::value;
    constexpr int kt = decltype(TT)::value * 64;     // shorts
    #pragma unroll
    for (int i = 0; i < 4; ++i) {
      __builtin_amdgcn_global_load_lds(
          (const __attribute__((address_space(1))) void*)(ga[i] + kt),
          (__attribute__((address_space(3))) void*)&As[cb][(w * 4 + i) * 512], 16, 0, 0);
      __builtin_amdgcn_global_load_lds(
          (const __attribute__((address_space(1))) void*)(gb[i] + kt),
          (__attribute__((address_space(3))) void*)&Bs[cb][(w * 4 + i) * 512], 16, 0, 0);
    }
  };
  auto comp = [&](auto CUR) {
    constexpr int cb = decltype(CUR)::value;
    #pragma unroll
    for (int kk = 0; kk < 64; kk += 32) {
      short8_t afr[4], bfr[4];
      #pragma unroll
      for (int m = 0; m < 4; ++m)
        afr[m] = *(const short8_t*)&As[cb][(wr + m * 16 + l15) * 64 + ((kk + kh) ^ sw)];
      #pragma unroll
      for (int n = 0; n < 4; ++n)
        bfr[n] = *(const short8_t*)&Bs[cb][(wc + n * 16 + l15) * 64 + ((kk + kh) ^ sw)];
      #pragma unroll
      for (int m = 0; m < 4; ++m)
        #pragma unroll
        for (int n = 0; n < 4; ++n)
          acc[m][n] = __builtin_amdgcn_mfma_f32_16x16x32_bf16(afr[m], bfr[n], acc[m][n], 0, 0, 0);
    }
  };

  stage(std::integral_constant<int, 0>{}, std::integral_constant<int, 0>{});
  __syncthreads();

  sfor<0, NT>([&](auto TT) {
    constexpr int t   = decltype(TT)::value;
    constexpr int cur = t & 1;
    if constexpr (t + 1 < NT)
      stage(std::integral_constant<int, cur ^ 1>{}, std::integral_constant<int, t + 1>{});
    comp(std::integral_constant<int, cur>{});
    if constexpr (t + 1 < NT) __syncthreads();
  });

  const int r4 = (lane >> 4) * 4;
  if constexpr (EPI == 0) {
    // cols [wc..wc+31] = hidden(e), [wc+32..wc+63] = gate(e): same lane holds both
    const int ebase = (bcol + wc) >> 1;
    #pragma unroll
    for (int m = 0; m < 4; ++m) {
      const int row = brow + wr + m * 16 + r4;
      #pragma unroll
      for (int n = 0; n < 2; ++n) {
        const int e = ebase + n * 16 + l15;
        const float bh = bias[e];
        const float bg = bias[E_ + e];
        #pragma unroll
        for (int j = 0; j < 4; ++j) {
          float hh = acc[m][n][j]     + bh;   // hidden pre-activation
          float gg = acc[m][n + 2][j] + bg;   // gate pre-activation
          float r  = fast_rcp(1.f + __expf(-fabsf(gg)));
          float z  = (gg >= 0.f) ? r : 1.f - r;   // sigmoid(gg)
          float a  = 1.f - z;                     // sigmoid(-gg)
          float gf = (hh >= 0.f) ? (hh + 0.5f) : fast_rcp(1.f + __expf(-hh));
          float bb = z * gf;
          ab_out[(size_t)(row + j) * E_ + e] = pk_bf16(a, bb);
        }
      }
    }
  } else {
    #pragma unroll
    for (int m = 0; m < 4; ++m) {
      #pragma unroll
      for (int n = 0; n < 4; ++n) {
        const int row = brow + wr + m * 16 + r4;
        const int col = bcol + wc + n * 16 + l15;
        #pragma unroll
        for (int j = 0; j < 4; ++j)
          c_out[(size_t)(row + j) * ldc + col] = acc[m][n][j] + bias[col];
      }
    }
  }
}

// ---------------------------------------------------------------- scan (3-pass)
__global__ __launch_bounds__(256) void scan_chunk(const unsigned* __restrict__ ab,
                                                  float* __restrict__ Ac,
                                                  float* __restrict__ Bc){
  const int c = blockIdx.x;
  const int e = (blockIdx.y * 256 + threadIdx.x) * 4;
  const int b = blockIdx.z;
  size_t base = (((size_t)b * T_ + (size_t)c * CT_) * E_ + e) >> 2;  // uint4 index
  const uint4* abv = (const uint4*)ab;
  float A0=1.f,A1=1.f,A2=1.f,A3=1.f, H0=0.f,H1=0.f,H2=0.f,H3=0.f;
  #pragma unroll 4
  for (int t = 0; t < CT_; ++t) {
    uint4 wv = abv[base + (size_t)t * (E_ / 4)];
    float a0=bf2f(wv.x&0xffffu), b0=bf2f(wv.x>>16);
    float a1=bf2f(wv.y&0xffffu), b1=bf2f(wv.y>>16);
    float a2=bf2f(wv.z&0xffffu), b2=bf2f(wv.z>>16);
    float a3=bf2f(wv.w&0xffffu), b3=bf2f(wv.w>>16);
    H0=fmaf(a0,H0,b0); H1=fmaf(a1,H1,b1); H2=fmaf(a2,H2,b2); H3=fmaf(a3,H3,b3);
    A0*=a0; A1*=a1; A2*=a2; A3*=a3;
  }
  size_t ci = (((size_t)b * NC_ + c) * E_ + e) >> 2;
  ((float4*)Ac)[ci] = (float4){A0,A1,A2,A3};
  ((float4*)Bc)[ci] = (float4){H0,H1,H2,H3};
}

// Initial hidden state is 1.0 (reference pads log_values with 0 -> exp(0)=1).
__global__ __launch_bounds__(256) void scan_carry(const float* __restrict__ Ac,
                                                  const float* __restrict__ Bc,
                                                  float* __restrict__ Hc){
  int idx = blockIdx.x * 256 + threadIdx.x;   // 0..B_*E_-1
  int b = idx >> 11;                          // /E_
  int e = idx & (E_ - 1);
  float H = 1.f;                              // h_0 = 1 !
  for (int c = 0; c < NC_; ++c) {
    size_t ci = ((size_t)b * NC_ + c) * E_ + e;
    float A = Ac[ci], Bv = Bc[ci];
    Hc[ci] = H;                               // carry-in for chunk c
    H = fmaf(A, H, Bv);
  }
}

__global__ __launch_bounds__(256) void scan_final(const unsigned* __restrict__ ab,
                                                  const float* __restrict__ Hc,
                                                  short* __restrict__ h){
  const int c = blockIdx.x;
  const int e = (blockIdx.y * 256 + threadIdx.x) * 4;
  const int b = blockIdx.z;
  size_t base = (((size_t)b * T_ + (size_t)c * CT_) * E_ + e) >> 2;
  const uint4* abv = (const uint4*)ab;
  float4 Hv = ((const float4*)Hc)[(((size_t)b * NC_ + c) * E_ + e) >> 2];
  float H0=Hv.x, H1=Hv.y, H2=Hv.z, H3=Hv.w;
  short4* hv = (short4*)h;
  #pragma unroll 4
  for (int t = 0; t < CT_; ++t) {
    uint4 wv = abv[base + (size_t)t * (E_ / 4)];
    H0 = fmaf(bf2f(wv.x&0xffffu), H0, bf2f(wv.x>>16));
    H1 = fmaf(bf2f(wv.y&0xffffu), H1, bf2f(wv.y>>16));
    H2 = fmaf(bf2f(wv.z&0xffffu), H2, bf2f(wv.z>>16));
    H3 = fmaf(bf2f(wv.w&0xffffu), H3, bf2f(wv.w>>16));
    short4 o;
    o.x=(short)f2bf(H0); o.y=(short)f2bf(H1); o.z=(short)f2bf(H2); o.w=(short)f2bf(H3);
    hv[base + (size_t)t * (E_ / 4)] = o;
  }
}

// ---------------------------------------------------------------- launch
extern "C" void kernel_launch(void* const* d_in, const int* in_sizes, int n_in,
                              void* d_out, int out_size, void* d_ws, size_t ws_size,
                              hipStream_t stream)
{
  const float* x     = (const float*)d_in[0];
  const float* W_hg  = (const float*)d_in[1];
  const float* b_hg  = (const float*)d_in[2];
  const float* W_out = (const float*)d_in[3];
  const float* b_out = (const float*)d_in[4];
  float* out = (float*)d_out;

  char* p = (char*)d_ws;
  auto carve = [&](size_t bytes) -> char* {
    char* q = p; p += (bytes + 255) & ~(size_t)255; return q;
  };
  short*    xb   = (short*)   carve((size_t)M_ * K1_ * 2);   // 16.8 MB
  short*    Wp   = (short*)   carve((size_t)N1_ * K1_ * 2);  //  4.2 MB
  short*    Wo   = (short*)   carve((size_t)N2_ * K2_ * 2);  //  2.1 MB
  unsigned* ab   = (unsigned*)carve((size_t)M_ * E_ * 4);    // 134.2 MB
  short*    hbuf = (short*)   carve((size_t)M_ * E_ * 2);    // 67.1 MB
  float*    Ac   = (float*)   carve((size_t)B_ * NC_ * E_ * 4);
  float*    Bc   = (float*)   carve((size_t)B_ * NC_ * E_ * 4);
  float*    Hc   = (float*)   carve((size_t)B_ * NC_ * E_ * 4);

  conv_f32_bf16_x4<<<(M_ * K1_ / 4 + 255) / 256, 256, 0, stream>>>(x, xb, M_ * K1_ / 4);
  conv_whg<<<N1_, 128, 0, stream>>>(W_hg, Wp);
  conv_f32_bf16_x4<<<(N2_ * K2_ / 4 + 255) / 256, 256, 0, stream>>>(W_out, Wo, N2_ * K2_ / 4);

  gemm_db<0, K1_><<<dim3(N1_ / 128, M_ / 128), 256, 0, stream>>>(xb, Wp, b_hg, ab, nullptr, 0);

  scan_chunk<<<dim3(NC_, E_ / 1024, B_), 256, 0, stream>>>(ab, Ac, Bc);
  scan_carry<<<(B_ * E_) / 256, 256, 0, stream>>>(Ac, Bc, Hc);
  scan_final<<<dim3(NC_, E_ / 1024, B_), 256, 0, stream>>>(ab, Hc, hbuf);

  gemm_db<1, K2_><<<dim3(N2_ / 128, M_ / 128), 256, 0, stream>>>(hbuf, Wo, b_out, nullptr, out, N2_);
}